// Round 1
// baseline (490.415 us; speedup 1.0000x reference)
//
#include <hip/hip_runtime.h>
#include <cstdint>
#include <cstddef>

#define M_ROWS 65536
#define N_COLS 1024
#define K_DIM  1024

typedef _Float16 f16x8 __attribute__((ext_vector_type(8)));
typedef float f32x4 __attribute__((ext_vector_type(4)));

// ---------------- prep: scale/bias ----------------
__global__ __launch_bounds__(256) void prep_scale_bias(
    const float* __restrict__ gamma, const float* __restrict__ beta,
    const float* __restrict__ mean, const float* __restrict__ var,
    float* __restrict__ bias, float* __restrict__ scale)
{
  int i = blockIdx.x * 256 + threadIdx.x;
  if (i < N_COLS) {
    float s = gamma[i] * rsqrtf(var[i] + 1e-3f);
    scale[i] = s;
    bias[i] = beta[i] - mean[i] * s;
  }
}

// ---------------- prep: W -> Wt (transposed, scaled, f16) ----------------
__global__ __launch_bounds__(256) void prep_wt(
    const float* __restrict__ W, const float* __restrict__ scale,
    _Float16* __restrict__ Wt)
{
  __shared__ float tile[64][68];
  int k0 = blockIdx.x * 64, n0 = blockIdx.y * 64;
  int t = threadIdx.x;
  int kr = t >> 2, q = t & 3;
  #pragma unroll
  for (int j = 0; j < 4; ++j) {
    float4 v = *(const float4*)(W + (size_t)(k0 + kr) * N_COLS + n0 + q * 16 + j * 4);
    *(float4*)(&tile[kr][q * 16 + j * 4]) = v;
  }
  __syncthreads();
  int nr = t >> 2;  // local n
  float sn = scale[n0 + nr];
  __align__(16) _Float16 h[16];
  #pragma unroll
  for (int j = 0; j < 16; ++j)
    h[j] = (_Float16)(tile[q * 16 + j][nr] * sn);
  uint4* dst = (uint4*)(Wt + (size_t)(n0 + nr) * K_DIM + k0 + q * 16);
  dst[0] = *(uint4*)(&h[0]);
  dst[1] = *(uint4*)(&h[8]);
}

// ---------------- GEMM: z = (A @ Wt^T + bias) * priors -> out ----------------
// 128x128 tile, BK=64, 4 waves (64x64 each), mfma_f32_16x16x32_f16,
// double-buffered LDS. A reg-staged fp32->f16, B via global_load_lds with
// pre-swizzled source. LDS rows XOR-swizzled: byte ^= (row&7)<<4.
__global__ __launch_bounds__(256, 2) void gemm_f16(
    const float* __restrict__ A, const _Float16* __restrict__ Wt,
    const float* __restrict__ bias, const float* __restrict__ priors,
    float* __restrict__ out)
{
  __shared__ char smem[65536];  // As[2] @0/16384, Bs[2] @32768/49152
  const int tid = threadIdx.x;
  const int lane = tid & 63, wid = tid >> 6;
  const int wm = wid >> 1, wn = wid & 1;

  // bijective XCD swizzle (nwg=4096, 4096%8==0)
  int orig = blockIdx.x;
  int wgid = (orig & 7) * 512 + (orig >> 3);
  int mb = wgid >> 3, nb = wgid & 7;
  const int m0 = mb * 128, n0 = nb * 128;

  f32x4 acc[4][4];
  #pragma unroll
  for (int i = 0; i < 4; ++i)
    #pragma unroll
    for (int j = 0; j < 4; ++j) acc[i][j] = (f32x4){0.f, 0.f, 0.f, 0.f};

  float4 areg[8];

  auto loadA = [&](int kt) {
    #pragma unroll
    for (int j = 0; j < 8; ++j) {
      int f = j * 256 + tid;       // float4 index into 128x64 fp32 tile
      int ml = f >> 4;             // 16 float4 per row (64 floats)
      int k4 = (f & 15) << 2;
      areg[j] = *(const float4*)(A + (size_t)(m0 + ml) * K_DIM + kt * 64 + k4);
    }
  };
  auto storeA = [&](int buf) {
    int base = buf * 16384;
    #pragma unroll
    for (int j = 0; j < 8; ++j) {
      int f = j * 256 + tid;
      int ml = f >> 4;
      int k4 = (f & 15) << 2;
      int off = ml * 128 + ((k4 * 2) ^ ((ml & 7) << 4));
      union { _Float16 h[4]; uint2 u; } p;
      p.h[0] = (_Float16)areg[j].x;
      p.h[1] = (_Float16)areg[j].y;
      p.h[2] = (_Float16)areg[j].z;
      p.h[3] = (_Float16)areg[j].w;
      *(uint2*)(&smem[base + off]) = p.u;
    }
  };
  auto issueB = [&](int kt, int buf) {
    int base = 32768 + buf * 16384;
    #pragma unroll
    for (int t4 = 0; t4 < 4; ++t4) {
      int ch = t4 * 256 + tid;     // 16B chunk index into 128x64 f16 tile
      int nl = ch >> 3, c = ch & 7;
      // linear LDS dest; inverse-swizzled global source (rule 21)
      const char* src = (const char*)Wt
          + ((size_t)(n0 + nl) * K_DIM + kt * 64) * 2
          + ((c * 16) ^ ((nl & 7) << 4));
      __builtin_amdgcn_global_load_lds(
          (const __attribute__((address_space(1))) unsigned int*)src,
          (__attribute__((address_space(3))) unsigned int*)(&smem[base + ch * 16]),
          16, 0, 0);
    }
  };

  loadA(0);
  issueB(0, 0);
  storeA(0);
  __syncthreads();

  for (int kt = 0; kt < 16; ++kt) {
    int cur = kt & 1, nxt = cur ^ 1;
    if (kt < 15) {
      loadA(kt + 1);
      issueB(kt + 1, nxt);
    }
    int ab = cur * 16384, bb = 32768 + cur * 16384;
    #pragma unroll
    for (int kc = 0; kc < 2; ++kc) {
      int k2 = (kc * 32 + ((lane >> 4) * 8)) * 2;
      f16x8 af[4], bf[4];
      #pragma unroll
      for (int fm = 0; fm < 4; ++fm) {
        int rl = wm * 64 + fm * 16 + (lane & 15);
        af[fm] = *(const f16x8*)(&smem[ab + rl * 128 + (k2 ^ ((rl & 7) << 4))]);
      }
      #pragma unroll
      for (int fn = 0; fn < 4; ++fn) {
        int nl = wn * 64 + fn * 16 + (lane & 15);
        bf[fn] = *(const f16x8*)(&smem[bb + nl * 128 + (k2 ^ ((nl & 7) << 4))]);
      }
      #pragma unroll
      for (int fm = 0; fm < 4; ++fm)
        #pragma unroll
        for (int fn = 0; fn < 4; ++fn)
          acc[fm][fn] = __builtin_amdgcn_mfma_f32_16x16x32_f16(af[fm], bf[fn], acc[fm][fn], 0, 0, 0);
    }
    if (kt < 15) storeA(nxt);
    __syncthreads();
  }

  // epilogue: + bias, * priors, write z
  #pragma unroll
  for (int fn = 0; fn < 4; ++fn) {
    int col = n0 + wn * 64 + fn * 16 + (lane & 15);
    float bv = bias[col];
    #pragma unroll
    for (int fm = 0; fm < 4; ++fm) {
      int row0 = m0 + wm * 64 + fm * 16 + ((lane >> 4) << 2);
      #pragma unroll
      for (int r = 0; r < 4; ++r) {
        size_t idx = (size_t)(row0 + r) * N_COLS + col;
        out[idx] = (acc[fm][fn][r] + bv) * priors[idx];
      }
    }
  }
}

// ---------------- sparsemax, in place on d_out, one wave per row ----------------
__global__ __launch_bounds__(256) void sparsemax_rows(float* __restrict__ z)
{
  const int lane = threadIdx.x & 63, wid = threadIdx.x >> 6;
  const size_t row = (size_t)blockIdx.x * 4 + wid;
  float* p = z + row * N_COLS;

  float v[16];
  #pragma unroll
  for (int j = 0; j < 4; ++j) {
    float4 t = *(const float4*)(p + j * 256 + lane * 4);
    v[j * 4 + 0] = t.x; v[j * 4 + 1] = t.y; v[j * 4 + 2] = t.z; v[j * 4 + 3] = t.w;
  }

  float mx = v[0];
  #pragma unroll
  for (int j = 1; j < 16; ++j) mx = fmaxf(mx, v[j]);
  #pragma unroll
  for (int m = 1; m <= 32; m <<= 1) mx = fmaxf(mx, __shfl_xor(mx, m, 64));

  // tau* in [mx-1, mx]; f(tau) = sum relu(z - tau) - 1, monotone decreasing
  float lo = mx - 1.0f, hi = mx;
  for (int it = 0; it < 12; ++it) {
    float tau = 0.5f * (lo + hi);
    float s = 0.f;
    #pragma unroll
    for (int j = 0; j < 16; ++j) s += fmaxf(v[j] - tau, 0.f);
    #pragma unroll
    for (int m = 1; m <= 32; m <<= 1) s += __shfl_xor(s, m, 64);
    if (s >= 1.f) lo = tau; else hi = tau;   // lane-uniform: butterfly sums identical
  }
  // exact polish: tau = (sum_{z>tau} z - 1) / k  (Newton on piecewise-linear f)
  float tau = lo;
  #pragma unroll
  for (int it = 0; it < 2; ++it) {
    float s = 0.f, k = 0.f;
    #pragma unroll
    for (int j = 0; j < 16; ++j) {
      bool g = v[j] > tau;
      s += g ? v[j] : 0.f;
      k += g ? 1.f : 0.f;
    }
    #pragma unroll
    for (int m = 1; m <= 32; m <<= 1) { s += __shfl_xor(s, m, 64); k += __shfl_xor(k, m, 64); }
    tau = (s - 1.f) / k;   // k >= 1 always (z=mx > tau)
  }

  #pragma unroll
  for (int j = 0; j < 4; ++j) {
    float4 t;
    t.x = fmaxf(v[j * 4 + 0] - tau, 0.f);
    t.y = fmaxf(v[j * 4 + 1] - tau, 0.f);
    t.z = fmaxf(v[j * 4 + 2] - tau, 0.f);
    t.w = fmaxf(v[j * 4 + 3] - tau, 0.f);
    *(float4*)(p + j * 256 + lane * 4) = t;
  }
}

// ---------------- launch ----------------
extern "C" void kernel_launch(void* const* d_in, const int* in_sizes, int n_in,
                              void* d_out, int out_size, void* d_ws, size_t ws_size,
                              hipStream_t stream) {
  const float* inputs = (const float*)d_in[0];
  const float* priors = (const float*)d_in[1];
  const float* W      = (const float*)d_in[2];
  const float* gamma  = (const float*)d_in[3];
  const float* beta   = (const float*)d_in[4];
  const float* mean   = (const float*)d_in[5];
  const float* var    = (const float*)d_in[6];
  float* out = (float*)d_out;

  char* ws = (char*)d_ws;
  float* bias  = (float*)ws;            // 4 KB
  float* scale = (float*)(ws + 4096);   // 4 KB
  _Float16* Wt = (_Float16*)(ws + 8192);// 2 MB, [N][K] transposed+scaled

  prep_scale_bias<<<4, 256, 0, stream>>>(gamma, beta, mean, var, bias, scale);
  prep_wt<<<dim3(16, 16), 256, 0, stream>>>(W, scale, Wt);
  gemm_f16<<<4096, 256, 0, stream>>>(inputs, Wt, bias, priors, out);
  sparsemax_rows<<<16384, 256, 0, stream>>>(out);
}

// Round 2
// 430.982 us; speedup vs baseline: 1.1379x; 1.1379x over previous
//
#include <hip/hip_runtime.h>
#include <cstdint>
#include <cstddef>

#define M_ROWS 65536
#define N_COLS 1024
#define K_DIM  1024

typedef _Float16 f16x8 __attribute__((ext_vector_type(8)));
typedef float f32x4 __attribute__((ext_vector_type(4)));

// ---------------- prep: scale/bias ----------------
__global__ __launch_bounds__(256) void prep_scale_bias(
    const float* __restrict__ gamma, const float* __restrict__ beta,
    const float* __restrict__ mean, const float* __restrict__ var,
    float* __restrict__ bias, float* __restrict__ scale)
{
  int i = blockIdx.x * 256 + threadIdx.x;
  if (i < N_COLS) {
    float s = gamma[i] * rsqrtf(var[i] + 1e-3f);
    scale[i] = s;
    bias[i] = beta[i] - mean[i] * s;
  }
}

// ---------------- prep: W -> Wt (transposed, scaled, f16) ----------------
__global__ __launch_bounds__(256) void prep_wt(
    const float* __restrict__ W, const float* __restrict__ scale,
    _Float16* __restrict__ Wt)
{
  __shared__ float tile[64][68];
  int k0 = blockIdx.x * 64, n0 = blockIdx.y * 64;
  int t = threadIdx.x;
  int kr = t >> 2, q = t & 3;
  #pragma unroll
  for (int j = 0; j < 4; ++j) {
    float4 v = *(const float4*)(W + (size_t)(k0 + kr) * N_COLS + n0 + q * 16 + j * 4);
    *(float4*)(&tile[kr][q * 16 + j * 4]) = v;
  }
  __syncthreads();
  int nr = t >> 2;  // local n
  float sn = scale[n0 + nr];
  __align__(16) _Float16 h[16];
  #pragma unroll
  for (int j = 0; j < 16; ++j)
    h[j] = (_Float16)(tile[q * 16 + j][nr] * sn);
  uint4* dst = (uint4*)(Wt + (size_t)(n0 + nr) * K_DIM + k0 + q * 16);
  dst[0] = *(uint4*)(&h[0]);
  dst[1] = *(uint4*)(&h[8]);
}

// ---------------- prep: A (fp32) -> Af (f16), grid-stride, vectorized ----------------
__global__ __launch_bounds__(256) void conv_a_f16(
    const float* __restrict__ A, _Float16* __restrict__ Af)
{
  const size_t total8 = (size_t)M_ROWS * K_DIM / 8;   // 8 elems per thread-iter
  size_t i = (size_t)blockIdx.x * 256 + threadIdx.x;
  const size_t stride = (size_t)gridDim.x * 256;
  for (; i < total8; i += stride) {
    float4 a = *(const float4*)(A + i * 8);
    float4 b = *(const float4*)(A + i * 8 + 4);
    union { _Float16 h[8]; uint4 u; } p;
    p.h[0] = (_Float16)a.x; p.h[1] = (_Float16)a.y;
    p.h[2] = (_Float16)a.z; p.h[3] = (_Float16)a.w;
    p.h[4] = (_Float16)b.x; p.h[5] = (_Float16)b.y;
    p.h[6] = (_Float16)b.z; p.h[7] = (_Float16)b.w;
    *(uint4*)(Af + i * 8) = p.u;
  }
}

// ---------------- FAST GEMM: both operands f16 via global_load_lds ----------------
// 128x128 tile, BK=64, 4 waves (64x64 each), mfma_f32_16x16x32_f16,
// double-buffered LDS, linear LDS dest + inverse-swizzled global source
// (rule 21), XOR-swizzled reads: byte ^= (row&7)<<4.
__global__ __launch_bounds__(256, 2) void gemm_f16_fast(
    const _Float16* __restrict__ Af, const _Float16* __restrict__ Wt,
    const float* __restrict__ bias, const float* __restrict__ priors,
    float* __restrict__ out)
{
  __shared__ char smem[65536];  // A0 @0, A1 @16384, B0 @32768, B1 @49152
  const int tid = threadIdx.x;
  const int lane = tid & 63, wid = tid >> 6;
  const int wm = wid >> 1, wn = wid & 1;

  // bijective XCD swizzle (nwg=4096, 4096%8==0)
  int orig = blockIdx.x;
  int wgid = (orig & 7) * 512 + (orig >> 3);
  int mb = wgid >> 3, nb = wgid & 7;
  const int m0 = mb * 128, n0 = nb * 128;

  f32x4 acc[4][4];
  #pragma unroll
  for (int i = 0; i < 4; ++i)
    #pragma unroll
    for (int j = 0; j < 4; ++j) acc[i][j] = (f32x4){0.f, 0.f, 0.f, 0.f};

  // stage one 128x64 f16 tile (16 KB) from `base` rows starting at rowBase
  auto issueTile = [&](const _Float16* base, int rowBase, int kt, int ldsOff) {
    #pragma unroll
    for (int t4 = 0; t4 < 4; ++t4) {
      int ch = t4 * 256 + tid;     // 16B chunk index, 1024 chunks
      int rl = ch >> 3, c = ch & 7;
      const char* src = (const char*)base
          + ((size_t)(rowBase + rl) * K_DIM + kt * 64) * 2
          + ((c * 16) ^ ((rl & 7) << 4));
      __builtin_amdgcn_global_load_lds(
          (const __attribute__((address_space(1))) unsigned int*)src,
          (__attribute__((address_space(3))) unsigned int*)(&smem[ldsOff + ch * 16]),
          16, 0, 0);
    }
  };

  issueTile(Af, m0, 0, 0);
  issueTile(Wt, n0, 0, 32768);
  __syncthreads();

  for (int kt = 0; kt < 16; ++kt) {
    int cur = kt & 1, nxt = cur ^ 1;
    if (kt < 15) {
      issueTile(Af, m0, kt + 1, nxt * 16384);
      issueTile(Wt, n0, kt + 1, 32768 + nxt * 16384);
    }
    int ab = cur * 16384, bb = 32768 + cur * 16384;
    #pragma unroll
    for (int kc = 0; kc < 2; ++kc) {
      int k2 = (kc * 32 + ((lane >> 4) * 8)) * 2;
      f16x8 af[4], bf[4];
      #pragma unroll
      for (int fm = 0; fm < 4; ++fm) {
        int rl = wm * 64 + fm * 16 + (lane & 15);
        af[fm] = *(const f16x8*)(&smem[ab + rl * 128 + (k2 ^ ((rl & 7) << 4))]);
      }
      #pragma unroll
      for (int fn = 0; fn < 4; ++fn) {
        int nl = wn * 64 + fn * 16 + (lane & 15);
        bf[fn] = *(const f16x8*)(&smem[bb + nl * 128 + (k2 ^ ((nl & 7) << 4))]);
      }
      #pragma unroll
      for (int fm = 0; fm < 4; ++fm)
        #pragma unroll
        for (int fn = 0; fn < 4; ++fn)
          acc[fm][fn] = __builtin_amdgcn_mfma_f32_16x16x32_f16(af[fm], bf[fn], acc[fm][fn], 0, 0, 0);
    }
    __syncthreads();
  }

  // epilogue: + bias, * priors, write z
  #pragma unroll
  for (int fn = 0; fn < 4; ++fn) {
    int col = n0 + wn * 64 + fn * 16 + (lane & 15);
    float bv = bias[col];
    #pragma unroll
    for (int fm = 0; fm < 4; ++fm) {
      int row0 = m0 + wm * 64 + fm * 16 + ((lane >> 4) << 2);
      #pragma unroll
      for (int r = 0; r < 4; ++r) {
        size_t idx = (size_t)(row0 + r) * N_COLS + col;
        out[idx] = (acc[fm][fn][r] + bv) * priors[idx];
      }
    }
  }
}

// ---------------- FALLBACK GEMM (round-1 kernel): A reg-staged fp32->f16 ----------------
__global__ __launch_bounds__(256, 2) void gemm_f16(
    const float* __restrict__ A, const _Float16* __restrict__ Wt,
    const float* __restrict__ bias, const float* __restrict__ priors,
    float* __restrict__ out)
{
  __shared__ char smem[65536];
  const int tid = threadIdx.x;
  const int lane = tid & 63, wid = tid >> 6;
  const int wm = wid >> 1, wn = wid & 1;

  int orig = blockIdx.x;
  int wgid = (orig & 7) * 512 + (orig >> 3);
  int mb = wgid >> 3, nb = wgid & 7;
  const int m0 = mb * 128, n0 = nb * 128;

  f32x4 acc[4][4];
  #pragma unroll
  for (int i = 0; i < 4; ++i)
    #pragma unroll
    for (int j = 0; j < 4; ++j) acc[i][j] = (f32x4){0.f, 0.f, 0.f, 0.f};

  float4 areg[8];

  auto loadA = [&](int kt) {
    #pragma unroll
    for (int j = 0; j < 8; ++j) {
      int f = j * 256 + tid;
      int ml = f >> 4;
      int k4 = (f & 15) << 2;
      areg[j] = *(const float4*)(A + (size_t)(m0 + ml) * K_DIM + kt * 64 + k4);
    }
  };
  auto storeA = [&](int buf) {
    int base = buf * 16384;
    #pragma unroll
    for (int j = 0; j < 8; ++j) {
      int f = j * 256 + tid;
      int ml = f >> 4;
      int k4 = (f & 15) << 2;
      int off = ml * 128 + ((k4 * 2) ^ ((ml & 7) << 4));
      union { _Float16 h[4]; uint2 u; } p;
      p.h[0] = (_Float16)areg[j].x;
      p.h[1] = (_Float16)areg[j].y;
      p.h[2] = (_Float16)areg[j].z;
      p.h[3] = (_Float16)areg[j].w;
      *(uint2*)(&smem[base + off]) = p.u;
    }
  };
  auto issueB = [&](int kt, int buf) {
    int base = 32768 + buf * 16384;
    #pragma unroll
    for (int t4 = 0; t4 < 4; ++t4) {
      int ch = t4 * 256 + tid;
      int nl = ch >> 3, c = ch & 7;
      const char* src = (const char*)Wt
          + ((size_t)(n0 + nl) * K_DIM + kt * 64) * 2
          + ((c * 16) ^ ((nl & 7) << 4));
      __builtin_amdgcn_global_load_lds(
          (const __attribute__((address_space(1))) unsigned int*)src,
          (__attribute__((address_space(3))) unsigned int*)(&smem[base + ch * 16]),
          16, 0, 0);
    }
  };

  loadA(0);
  issueB(0, 0);
  storeA(0);
  __syncthreads();

  for (int kt = 0; kt < 16; ++kt) {
    int cur = kt & 1, nxt = cur ^ 1;
    if (kt < 15) {
      loadA(kt + 1);
      issueB(kt + 1, nxt);
    }
    int ab = cur * 16384, bb = 32768 + cur * 16384;
    #pragma unroll
    for (int kc = 0; kc < 2; ++kc) {
      int k2 = (kc * 32 + ((lane >> 4) * 8)) * 2;
      f16x8 af[4], bf[4];
      #pragma unroll
      for (int fm = 0; fm < 4; ++fm) {
        int rl = wm * 64 + fm * 16 + (lane & 15);
        af[fm] = *(const f16x8*)(&smem[ab + rl * 128 + (k2 ^ ((rl & 7) << 4))]);
      }
      #pragma unroll
      for (int fn = 0; fn < 4; ++fn) {
        int nl = wn * 64 + fn * 16 + (lane & 15);
        bf[fn] = *(const f16x8*)(&smem[bb + nl * 128 + (k2 ^ ((nl & 7) << 4))]);
      }
      #pragma unroll
      for (int fm = 0; fm < 4; ++fm)
        #pragma unroll
        for (int fn = 0; fn < 4; ++fn)
          acc[fm][fn] = __builtin_amdgcn_mfma_f32_16x16x32_f16(af[fm], bf[fn], acc[fm][fn], 0, 0, 0);
    }
    if (kt < 15) storeA(nxt);
    __syncthreads();
  }

  #pragma unroll
  for (int fn = 0; fn < 4; ++fn) {
    int col = n0 + wn * 64 + fn * 16 + (lane & 15);
    float bv = bias[col];
    #pragma unroll
    for (int fm = 0; fm < 4; ++fm) {
      int row0 = m0 + wm * 64 + fm * 16 + ((lane >> 4) << 2);
      #pragma unroll
      for (int r = 0; r < 4; ++r) {
        size_t idx = (size_t)(row0 + r) * N_COLS + col;
        out[idx] = (acc[fm][fn][r] + bv) * priors[idx];
      }
    }
  }
}

// ---------------- sparsemax, in place on d_out, one wave per row ----------------
__global__ __launch_bounds__(256) void sparsemax_rows(float* __restrict__ z)
{
  const int lane = threadIdx.x & 63, wid = threadIdx.x >> 6;
  const size_t row = (size_t)blockIdx.x * 4 + wid;
  float* p = z + row * N_COLS;

  float v[16];
  #pragma unroll
  for (int j = 0; j < 4; ++j) {
    float4 t = *(const float4*)(p + j * 256 + lane * 4);
    v[j * 4 + 0] = t.x; v[j * 4 + 1] = t.y; v[j * 4 + 2] = t.z; v[j * 4 + 3] = t.w;
  }

  float mx = v[0];
  #pragma unroll
  for (int j = 1; j < 16; ++j) mx = fmaxf(mx, v[j]);
  #pragma unroll
  for (int m = 1; m <= 32; m <<= 1) mx = fmaxf(mx, __shfl_xor(mx, m, 64));

  float lo = mx - 1.0f, hi = mx;
  for (int it = 0; it < 12; ++it) {
    float tau = 0.5f * (lo + hi);
    float s = 0.f;
    #pragma unroll
    for (int j = 0; j < 16; ++j) s += fmaxf(v[j] - tau, 0.f);
    #pragma unroll
    for (int m = 1; m <= 32; m <<= 1) s += __shfl_xor(s, m, 64);
    if (s >= 1.f) lo = tau; else hi = tau;
  }
  float tau = lo;
  #pragma unroll
  for (int it = 0; it < 2; ++it) {
    float s = 0.f, k = 0.f;
    #pragma unroll
    for (int j = 0; j < 16; ++j) {
      bool g = v[j] > tau;
      s += g ? v[j] : 0.f;
      k += g ? 1.f : 0.f;
    }
    #pragma unroll
    for (int m = 1; m <= 32; m <<= 1) { s += __shfl_xor(s, m, 64); k += __shfl_xor(k, m, 64); }
    tau = (s - 1.f) / k;
  }

  #pragma unroll
  for (int j = 0; j < 4; ++j) {
    float4 t;
    t.x = fmaxf(v[j * 4 + 0] - tau, 0.f);
    t.y = fmaxf(v[j * 4 + 1] - tau, 0.f);
    t.z = fmaxf(v[j * 4 + 2] - tau, 0.f);
    t.w = fmaxf(v[j * 4 + 3] - tau, 0.f);
    *(float4*)(p + j * 256 + lane * 4) = t;
  }
}

// ---------------- launch ----------------
extern "C" void kernel_launch(void* const* d_in, const int* in_sizes, int n_in,
                              void* d_out, int out_size, void* d_ws, size_t ws_size,
                              hipStream_t stream) {
  const float* inputs = (const float*)d_in[0];
  const float* priors = (const float*)d_in[1];
  const float* W      = (const float*)d_in[2];
  const float* gamma  = (const float*)d_in[3];
  const float* beta   = (const float*)d_in[4];
  const float* mean   = (const float*)d_in[5];
  const float* var    = (const float*)d_in[6];
  float* out = (float*)d_out;

  char* ws = (char*)d_ws;
  float* bias  = (float*)ws;                 // 4 KB
  float* scale = (float*)(ws + 4096);        // 4 KB
  _Float16* Wt = (_Float16*)(ws + 8192);     // 2 MB, [N][K] transposed+scaled
  const size_t AF_OFF = 8192 + (size_t)N_COLS * K_DIM * 2;   // 2105344
  _Float16* Af = (_Float16*)(ws + AF_OFF);   // 134 MB, [M][K] f16
  const size_t need = AF_OFF + (size_t)M_ROWS * K_DIM * 2;

  prep_scale_bias<<<4, 256, 0, stream>>>(gamma, beta, mean, var, bias, scale);
  prep_wt<<<dim3(16, 16), 256, 0, stream>>>(W, scale, Wt);

  if (ws_size >= need) {
    conv_a_f16<<<2048, 256, 0, stream>>>(inputs, Af);
    gemm_f16_fast<<<4096, 256, 0, stream>>>(Af, Wt, bias, priors, out);
  } else {
    gemm_f16<<<4096, 256, 0, stream>>>(inputs, Wt, bias, priors, out);
  }
  sparsemax_rows<<<16384, 256, 0, stream>>>(out);
}